// Round 16
// baseline (709.294 us; speedup 1.0000x reference)
//
#include <hip/hip_runtime.h>
#include <hip/hip_bf16.h>

// Problem constants
constexpr int NB = 4;        // batch
constexpr int CC = 128;      // channels
constexpr int HW = 65536;    // 256*256 pixels per (b, channel) plane
// windows: 32x32 = 1024 per batch, 8x8 = 64 px per window

using bf16x8 = __attribute__((ext_vector_type(8))) short;   // MFMA A/B frag (4 VGPR)
using f32x4  = __attribute__((ext_vector_type(4))) float;   // MFMA C/D frag

__device__ __forceinline__ unsigned short f2bf(float f) {
  unsigned u = __builtin_bit_cast(unsigned, f);
  u += 0x7FFFu + ((u >> 16) & 1u);
  return (unsigned short)(u >> 16);
}
__device__ __forceinline__ float bf2f(unsigned short s) {
  return __builtin_bit_cast(float, (unsigned)s << 16);
}

// LDS-only barrier (r15): avoids __syncthreads' implicit vmcnt(0) drain of
// prefetched loads / fire-and-forget stores. All barriers guard LDS only.
__device__ __forceinline__ void lds_barrier() {
  __builtin_amdgcn_sched_barrier(0);
  asm volatile("s_waitcnt lgkmcnt(0)" ::: "memory");
  __builtin_amdgcn_s_barrier();
  __builtin_amdgcn_sched_barrier(0);
}

// Swizzled byte offsets (T2, r11-proven): rows of 128 B / 256 B.
__device__ __forceinline__ int swz128(int row, int b) { return row * 128 + (b ^ ((row & 7) << 4)); }
__device__ __forceinline__ int swz256(int row, int b) { return row * 256 + (b ^ ((row & 15) << 4)); }

// Load the 3 input rows (main 8 px + packed left/right halo) for one (ch, pr)
// dw task straight into registers (no LDS round-trip; zero cross-thread reuse).
__device__ __forceinline__ void dw_load3(const __hip_bfloat16* __restrict__ base,
                                         int ch, int ih0, int iw0, int pr,
                                         uint4* __restrict__ m,
                                         unsigned* __restrict__ lr) {
#pragma unroll
  for (int kr = 0; kr < 3; ++kr) {
    int ii = ih0 + pr - 1 + kr;
    uint4 mv = {0u, 0u, 0u, 0u};
    unsigned lo = 0, hi = 0;
    if ((unsigned)ii < 256u) {
      const __hip_bfloat16* row = base + (((size_t)ch) << 16) + (ii << 8);
      mv = *(const uint4*)(row + iw0);                 // iw0 mult of 8 -> 16B aligned
      if (iw0 > 0)   lo = (unsigned)__builtin_bit_cast(unsigned short, row[iw0 - 1]);
      if (iw0 < 248) hi = (unsigned)__builtin_bit_cast(unsigned short, row[iw0 + 8]);
    }
    m[kr] = mv;
    lr[kr] = lo | (hi << 16);   // low = left halo, high = right halo
  }
}

// dw 3x3 for one (ch, pr) output row of 8 px, inputs in registers.
__device__ __forceinline__ void dw_regs(const uint4* __restrict__ m,
                                        const unsigned* __restrict__ lr,
                                        const float* __restrict__ wd,
                                        float* __restrict__ outv) {
#pragma unroll
  for (int pc = 0; pc < 8; ++pc) outv[pc] = 0.f;
#pragma unroll
  for (int kr = 0; kr < 3; ++kr) {
    uint4 rw = m[kr];
    float rv[10];
    rv[0] = bf2f((unsigned short)(rw.x & 0xFFFFu));
    rv[1] = bf2f((unsigned short)(rw.x >> 16));
    rv[2] = bf2f((unsigned short)(rw.y & 0xFFFFu));
    rv[3] = bf2f((unsigned short)(rw.y >> 16));
    rv[4] = bf2f((unsigned short)(rw.z & 0xFFFFu));
    rv[5] = bf2f((unsigned short)(rw.z >> 16));
    rv[6] = bf2f((unsigned short)(rw.w & 0xFFFFu));
    rv[7] = bf2f((unsigned short)(rw.w >> 16));
    rv[8] = bf2f((unsigned short)(lr[kr] >> 16));      // right
    rv[9] = bf2f((unsigned short)(lr[kr] & 0xFFFFu));  // left
#pragma unroll
    for (int s = 0; s < 3; ++s) {
      float wv = wd[kr * 3 + s];
#pragma unroll
      for (int pc = 0; pc < 8; ++pc) {
        int mm = pc + s - 1;
        float xv = (mm < 0) ? rv[9] : rv[mm];
        outv[pc] = fmaf(wv, xv, outv[pc]);
      }
    }
  }
}

// =======================================================================
// Kernel 1: rolled 1x1 conv as bf16 MFMA GEMM (proven, unchanged).
// =======================================================================
__global__ __launch_bounds__(256) void k_qkv_mfma(const float* __restrict__ x,
                                                  const float* __restrict__ wq,
                                                  __hip_bfloat16* __restrict__ qkv) {
  __shared__ unsigned short x_s[128 * 136];   // [px][c]

  int blk = blockIdx.x;                 // 4 b x 256 i x 2 j-half
  int b = blk >> 9, i = (blk >> 1) & 255, jh = blk & 1;
  int j0 = jh << 7;
  int si = (i + 4) & 255;               // roll(-4): source row
  int t = threadIdx.x;

  {
    int c0 = (t & 63) << 1;
    int jb = (t >> 6) << 5;
    const float* xr0 = x + (((size_t)(b * CC + c0)) << 16) + (si << 8);
    const float* xr1 = xr0 + HW;
#pragma unroll
    for (int u = 0; u < 8; ++u) {
      int jj = jb + (u << 2);
      int sj = j0 + jj + 4;
      float v0[4], v1[4];
      if (sj + 3 <= 255) {
        *(float4*)v0 = *(const float4*)(xr0 + sj);
        *(float4*)v1 = *(const float4*)(xr1 + sj);
      } else {
#pragma unroll
        for (int e = 0; e < 4; ++e) {
          int s = (sj + e) & 255;
          v0[e] = xr0[s];
          v1[e] = xr1[s];
        }
      }
#pragma unroll
      for (int e = 0; e < 4; ++e) {
        unsigned pk = (unsigned)f2bf(v0[e]) | ((unsigned)f2bf(v1[e]) << 16);
        *(unsigned*)&x_s[(jj + e) * 136 + c0] = pk;
      }
    }
  }
  __syncthreads();

  int w = t >> 6;
  int lane = t & 63;
  int col = lane & 15;
  int kg = lane >> 4;

#pragma unroll 1
  for (int oi = 0; oi < 3; ++oi) {
    int m0 = oi * 128 + w * 32;
    bf16x8 afr[2][4];
#pragma unroll
    for (int mt = 0; mt < 2; ++mt) {
      const float* wr = wq + (m0 + mt * 16 + col) * CC + kg * 8;
#pragma unroll
      for (int ks = 0; ks < 4; ++ks) {
        float wa[4], wb[4];
        *(float4*)wa = *(const float4*)(wr + ks * 32);
        *(float4*)wb = *(const float4*)(wr + ks * 32 + 4);
        bf16x8 f;
#pragma unroll
        for (int e = 0; e < 4; ++e) {
          f[e] = (short)f2bf(wa[e]);
          f[e + 4] = (short)f2bf(wb[e]);
        }
        afr[mt][ks] = f;
      }
    }
#pragma unroll 1
    for (int n = 0; n < 8; ++n) {
      int px = n * 16 + col;
      f32x4 acc0 = {0.f, 0.f, 0.f, 0.f};
      f32x4 acc1 = {0.f, 0.f, 0.f, 0.f};
#pragma unroll
      for (int ks = 0; ks < 4; ++ks) {
        bf16x8 bfr = *(const bf16x8*)&x_s[px * 136 + ks * 32 + kg * 8];
        acc0 = __builtin_amdgcn_mfma_f32_16x16x32_bf16(afr[0][ks], bfr, acc0, 0, 0, 0);
        acc1 = __builtin_amdgcn_mfma_f32_16x16x32_bf16(afr[1][ks], bfr, acc1, 0, 0, 0);
      }
      int j = j0 + n * 16 + col;
#pragma unroll
      for (int r = 0; r < 4; ++r) {
        int och0 = m0 + kg * 4 + r;
        int och1 = m0 + 16 + kg * 4 + r;
        int g0 = och0 >> 7, c0 = och0 & 127;
        int g1 = och1 >> 7, c1 = och1 & 127;
        qkv[(((size_t)((g0 * NB + b) * CC + c0)) << 16) + (i << 8) + j] =
            __float2bfloat16(acc0[r]);
        qkv[(((size_t)((g1 * NB + b) * CC + c1)) << 16) + (i << 8) + j] =
            __float2bfloat16(acc1[r]);
      }
    }
  }
}

// =======================================================================
// Kernel 2 (FUSED, TWO WINDOWS PER BLOCK): threads 0-255 = window 2p,
// threads 256-511 = window 2p+1, each with a private 33792 B LDS region
// (r14 layout). Per-thread work identical to r14; the two windows' phases
// interleave on the SIMDs so each window's latency chains hide under the
// other's issue. 67584 B LDS -> 2 blocks/CU = 4 windows in flight
// (guaranteed in-block, not reliant on multi-block residency).
// =======================================================================
__global__ __launch_bounds__(512) void k_fused(const __hip_bfloat16* __restrict__ qkv,
                                               const float* __restrict__ wdw,
                                               const float* __restrict__ temp_p,
                                               const float* __restrict__ wp,
                                               float* __restrict__ attn_out,
                                               float* __restrict__ y) {
  __shared__ __align__(16) char smem[67584];

  int t512 = threadIdx.x;
  int win = t512 >> 8;            // 0 or 1: which window this half-block owns
  int t = t512 & 255;
  char* RB = smem + win * 33792;
  char* RC = RB + 16384;
  float* sq = (float*)(RB + 32768);   // 256 floats

  int bid = blockIdx.x;                       // 2048 blocks = 2048 pairs
  int pair = ((bid & 7) << 8) + (bid >> 3);   // XCD swizzle (2048 % 8 == 0)
  int blk = pair * 2 + win;                   // logical window id
  int b = blk >> 10, n = blk & 1023;
  int ih0 = (n >> 5) << 3, iw0 = (n & 31) << 3;
  int ch_l = t & 15, grp = t >> 4;
  int pr = grp & 7, contrib = grp >> 3;      // 4 dw tasks share pr
  int wv = t >> 6, lane = t & 63;
  int col = lane & 15, kg = lane >> 4;
  float tau = temp_p[0];
  const __hip_bfloat16* qb = qkv + (((size_t)(b * CC)) << 16);
  const __hip_bfloat16* kb = qb + (((size_t)(NB * CC)) << 16);
  const __hip_bfloat16* vb = qb + (((size_t)(2 * NB * CC)) << 16);

  uint4 m[12];
  unsigned lr[12];
  float outv[4][8];
  float ssq[8];

  // ---- P0: q loads -> regs; dw q; ssq -> LDS
#pragma unroll
  for (int itk = 0; itk < 4; ++itk) {
    int ch = ((contrib + 2 * itk) << 4) + ch_l;
    dw_load3(qb, ch, ih0, iw0, pr, &m[itk * 3], &lr[itk * 3]);
  }
#pragma unroll
  for (int pc = 0; pc < 8; ++pc) ssq[pc] = 0.f;
#pragma unroll
  for (int itk = 0; itk < 4; ++itk) {
    int ch = ((contrib + 2 * itk) << 4) + ch_l;
    float wd[9];
#pragma unroll
    for (int kk = 0; kk < 9; ++kk) wd[kk] = wdw[ch * 9 + kk];
    dw_regs(&m[itk * 3], &lr[itk * 3], wd, outv[itk]);
#pragma unroll
    for (int pc = 0; pc < 8; ++pc) ssq[pc] = fmaf(outv[itk][pc], outv[itk][pc], ssq[pc]);
  }
#pragma unroll
  for (int pc = 0; pc < 8; ++pc) {
    float s = ssq[pc];
    s += __shfl_xor(s, 1); s += __shfl_xor(s, 2);
    s += __shfl_xor(s, 4); s += __shfl_xor(s, 8);
    ssq[pc] = s;
  }
  if (ch_l == 0) {
#pragma unroll
    for (int pc = 0; pc < 8; ++pc) sq[contrib * 64 + pr * 8 + pc] = ssq[pc];
  }
  lds_barrier();                                     // B1 (q ssq ready)

  // ---- P1: issue k loads; q scale + q_t write; dw k; k ssq -> LDS
  {
    uint4 m2[12];
    unsigned lr2[12];
#pragma unroll
    for (int itk = 0; itk < 4; ++itk) {
      int ch = ((contrib + 2 * itk) << 4) + ch_l;
      dw_load3(kb, ch, ih0, iw0, pr, &m2[itk * 3], &lr2[itk * 3]);
    }
    {
      float psv[8];
#pragma unroll
      for (int pc = 0; pc < 8; ++pc) {
        float s = sq[pr * 8 + pc] + sq[64 + pr * 8 + pc];
        psv[pc] = 1.f / fmaxf(sqrtf(s), 1e-12f);
      }
#pragma unroll
      for (int itk = 0; itk < 4; ++itk) {
        int ch = ((contrib + 2 * itk) << 4) + ch_l;
        unsigned short o8[8];
#pragma unroll
        for (int pc = 0; pc < 8; ++pc) o8[pc] = f2bf(outv[itk][pc] * psv[pc]);
        *(uint4*)(RB + swz128(ch, pr * 16)) = *(const uint4*)o8;
      }
    }
#pragma unroll
    for (int pc = 0; pc < 8; ++pc) ssq[pc] = 0.f;
#pragma unroll
    for (int itk = 0; itk < 4; ++itk) {
      int ch = ((contrib + 2 * itk) << 4) + ch_l;
      float wd[9];
#pragma unroll
      for (int kk = 0; kk < 9; ++kk) wd[kk] = wdw[(CC + ch) * 9 + kk];
      dw_regs(&m2[itk * 3], &lr2[itk * 3], wd, outv[itk]);
#pragma unroll
      for (int pc = 0; pc < 8; ++pc) ssq[pc] = fmaf(outv[itk][pc], outv[itk][pc], ssq[pc]);
    }
  }
#pragma unroll
  for (int pc = 0; pc < 8; ++pc) {
    float s = ssq[pc];
    s += __shfl_xor(s, 1); s += __shfl_xor(s, 2);
    s += __shfl_xor(s, 4); s += __shfl_xor(s, 8);
    ssq[pc] = s;
  }
  if (ch_l == 0) {
#pragma unroll
    for (int pc = 0; pc < 8; ++pc) sq[128 + contrib * 64 + pr * 8 + pc] = ssq[pc];
  }
  lds_barrier();                                     // B2 (k ssq ready)

  // ---- P2: k scale (tau folded) + k_t write
  {
    float psv[8];
#pragma unroll
    for (int pc = 0; pc < 8; ++pc) {
      float s = sq[128 + pr * 8 + pc] + sq[192 + pr * 8 + pc];
      psv[pc] = tau / fmaxf(sqrtf(s), 1e-12f);
    }
#pragma unroll
    for (int itk = 0; itk < 4; ++itk) {
      int ch = ((contrib + 2 * itk) << 4) + ch_l;
      unsigned short o8[8];
#pragma unroll
      for (int pc = 0; pc < 8; ++pc) o8[pc] = f2bf(outv[itk][pc] * psv[pc]);
      *(uint4*)(RC + swz128(ch, pr * 16)) = *(const uint4*)o8;
    }
  }
  lds_barrier();                                     // B3 (q_t + k_t ready)

  // ---- P3: QK^T; relu; attn fp32 write; keep pa; issue v loads
  int c0 = wv * 32;
  f32x4 pa0[8], pa1[8];
  {
    bf16x8 afr[2][2];
#pragma unroll
    for (int mt = 0; mt < 2; ++mt)
#pragma unroll
      for (int ks = 0; ks < 2; ++ks)
        afr[mt][ks] = *(const bf16x8*)(RB + swz128(c0 + mt * 16 + col, ks * 64 + kg * 16));
    float* ao = attn_out + ((size_t)blk << 14);   // 128*128 per window
#pragma unroll
    for (int dt = 0; dt < 8; ++dt) {
      bf16x8 b0 = *(const bf16x8*)(RC + swz128(dt * 16 + col, kg * 16));
      bf16x8 b1 = *(const bf16x8*)(RC + swz128(dt * 16 + col, 64 + kg * 16));
      f32x4 a0 = {0.f, 0.f, 0.f, 0.f};
      f32x4 a1 = {0.f, 0.f, 0.f, 0.f};
      a0 = __builtin_amdgcn_mfma_f32_16x16x32_bf16(afr[0][0], b0, a0, 0, 0, 0);
      a0 = __builtin_amdgcn_mfma_f32_16x16x32_bf16(afr[0][1], b1, a0, 0, 0, 0);
      a1 = __builtin_amdgcn_mfma_f32_16x16x32_bf16(afr[1][0], b0, a1, 0, 0, 0);
      a1 = __builtin_amdgcn_mfma_f32_16x16x32_bf16(afr[1][1], b1, a1, 0, 0, 0);
#pragma unroll
      for (int r = 0; r < 4; ++r) {
        a0[r] = fmaxf(a0[r], 0.f);
        a1[r] = fmaxf(a1[r], 0.f);
        ao[((c0 + kg * 4 + r) << 7) + dt * 16 + col] = a0[r];
        ao[((c0 + 16 + kg * 4 + r) << 7) + dt * 16 + col] = a1[r];
      }
      pa0[dt] = a0;
      pa1[dt] = a1;
    }
  }
#pragma unroll
  for (int itk = 0; itk < 4; ++itk) {
    int ch = ((contrib + 2 * itk) << 4) + ch_l;
    dw_load3(vb, ch, ih0, iw0, pr, &m[itk * 3], &lr[itk * 3]);
  }
  lds_barrier();                                     // B4 (q_t/k_t reads done)

  // ---- P4: dw v -> v_t [p][c] swz256 (over dead q_t); waves 0,1 a_t half0
#pragma unroll
  for (int itk = 0; itk < 4; ++itk) {
    int ch = ((contrib + 2 * itk) << 4) + ch_l;
    float wd[9];
#pragma unroll
    for (int kk = 0; kk < 9; ++kk) wd[kk] = wdw[(2 * CC + ch) * 9 + kk];
    float vo[8];
    dw_regs(&m[itk * 3], &lr[itk * 3], wd, vo);
#pragma unroll
    for (int pc = 0; pc < 8; ++pc)
      *(unsigned short*)(RB + swz256(pr * 8 + pc, ch * 2)) = f2bf(vo[pc]);
  }
  if (wv < 2) {
#pragma unroll
    for (int dt = 0; dt < 8; ++dt)
#pragma unroll
      for (int r = 0; r < 4; ++r) {
        int d = dt * 16 + col;
        *(unsigned short*)(RC + swz128(d, (c0 + kg * 4 + r) * 2)) = f2bf(pa0[dt][r]);
        *(unsigned short*)(RC + swz128(d, (c0 + 16 + kg * 4 + r) * 2)) = f2bf(pa1[dt][r]);
      }
  }
  lds_barrier();                                     // B5 (v_t + a_t half0 ready)

  // ---- P5: PV part1 (ks 0,1 -> c 0..63)
  f32x4 pacc[8];
#pragma unroll
  for (int dt = 0; dt < 8; ++dt) pacc[dt] = {0.f, 0.f, 0.f, 0.f};
#pragma unroll
  for (int ks = 0; ks < 2; ++ks) {
    bf16x8 va = *(const bf16x8*)(RB + swz256(wv * 16 + col, ks * 64 + kg * 16));
#pragma unroll
    for (int dt = 0; dt < 8; ++dt) {
      bf16x8 bf = *(const bf16x8*)(RC + swz128(dt * 16 + col, (ks & 1) * 64 + kg * 16));
      pacc[dt] = __builtin_amdgcn_mfma_f32_16x16x32_bf16(va, bf, pacc[dt], 0, 0, 0);
    }
  }
  lds_barrier();                                     // B6 (half0 reads done)

  // ---- P6: waves 2,3 write a_t half1 (c 64..127)
  if (wv >= 2) {
    int cl0 = c0 - 64;   // 0 or 32
#pragma unroll
    for (int dt = 0; dt < 8; ++dt)
#pragma unroll
      for (int r = 0; r < 4; ++r) {
        int d = dt * 16 + col;
        *(unsigned short*)(RC + swz128(d, (cl0 + kg * 4 + r) * 2)) = f2bf(pa0[dt][r]);
        *(unsigned short*)(RC + swz128(d, (cl0 + 16 + kg * 4 + r) * 2)) = f2bf(pa1[dt][r]);
      }
  }
  lds_barrier();                                     // B7 (a_t half1 ready)

  // ---- P7: PV part2 (ks 2,3 -> c 64..127)
#pragma unroll
  for (int ks = 2; ks < 4; ++ks) {
    bf16x8 va = *(const bf16x8*)(RB + swz256(wv * 16 + col, ks * 64 + kg * 16));
#pragma unroll
    for (int dt = 0; dt < 8; ++dt) {
      bf16x8 bf = *(const bf16x8*)(RC + swz128(dt * 16 + col, (ks & 1) * 64 + kg * 16));
      pacc[dt] = __builtin_amdgcn_mfma_f32_16x16x32_bf16(va, bf, pacc[dt], 0, 0, 0);
    }
  }
  lds_barrier();                                     // B8 (v_t reads done)

  // ---- P8: po_t [p][d] swz256 (over dead v_t)
#pragma unroll
  for (int dt = 0; dt < 8; ++dt)
#pragma unroll
    for (int r = 0; r < 4; ++r)
      *(unsigned short*)(RB + swz256(wv * 16 + kg * 4 + r, (dt * 16 + col) * 2)) =
          f2bf(pacc[dt][r]);
  lds_barrier();                                     // B9 (po_t ready)

  // ---- P9: proj (Wp A-frags from global, L2-resident) + fused unwindow/roll
  {
    int p = wv * 16 + col;
    bf16x8 bfr[4];
#pragma unroll
    for (int ks = 0; ks < 4; ++ks)
      bfr[ks] = *(const bf16x8*)(RB + swz256(p, ks * 64 + kg * 16));
    int i_f = (((n >> 5) << 3) + (p >> 3) + 4) & 255;
    int j_f = (((n & 31) << 3) + (p & 7) + 4) & 255;
    float* yp = y + (((size_t)b * CC) << 16) + (i_f << 8) + j_f;
#pragma unroll
    for (int mt = 0; mt < 8; ++mt) {
      bf16x8 afr[4];
      const float* wr = wp + (mt * 16 + col) * CC + kg * 8;
#pragma unroll
      for (int ks = 0; ks < 4; ++ks) {
        float wa[4], wb[4];
        *(float4*)wa = *(const float4*)(wr + ks * 32);
        *(float4*)wb = *(const float4*)(wr + ks * 32 + 4);
        bf16x8 f;
#pragma unroll
        for (int e = 0; e < 4; ++e) {
          f[e] = (short)f2bf(wa[e]);
          f[e + 4] = (short)f2bf(wb[e]);
        }
        afr[ks] = f;
      }
      f32x4 acc = {0.f, 0.f, 0.f, 0.f};
#pragma unroll
      for (int ks = 0; ks < 4; ++ks)
        acc = __builtin_amdgcn_mfma_f32_16x16x32_bf16(afr[ks], bfr[ks], acc, 0, 0, 0);
#pragma unroll
      for (int r = 0; r < 4; ++r) {
        int och = mt * 16 + kg * 4 + r;
        yp[(size_t)och << 16] = acc[r];
      }
    }
  }
}

extern "C" void kernel_launch(void* const* d_in, const int* in_sizes, int n_in,
                              void* d_out, int out_size, void* d_ws, size_t ws_size,
                              hipStream_t stream) {
  const float* x = (const float*)d_in[0];
  const float* w_qkv = (const float*)d_in[1];
  const float* w_dw = (const float*)d_in[2];
  const float* w_proj = (const float*)d_in[3];
  const float* temp = (const float*)d_in[4];
  float* y = (float*)d_out;
  float* attn = (float*)d_out + (size_t)NB * CC * HW;   // y first, then attn

  // d_ws (bf16): qkv [3][b][c][hw] = 201 MB.
  __hip_bfloat16* qkv = (__hip_bfloat16*)d_ws;

  k_qkv_mfma<<<2048, 256, 0, stream>>>(x, w_qkv, qkv);
  k_fused<<<2048, 512, 0, stream>>>(qkv, w_dw, temp, w_proj, attn, y);
}

// Round 17
// 652.023 us; speedup vs baseline: 1.0878x; 1.0878x over previous
//
#include <hip/hip_runtime.h>
#include <hip/hip_bf16.h>

// Problem constants
constexpr int NB = 4;        // batch
constexpr int CC = 128;      // channels
constexpr int HW = 65536;    // 256*256 pixels per (b, channel) plane
// windows: 32x32 = 1024 per batch, 8x8 = 64 px per window

using bf16x8 = __attribute__((ext_vector_type(8))) short;   // MFMA A/B frag (4 VGPR)
using f32x4  = __attribute__((ext_vector_type(4))) float;   // MFMA C/D frag

__device__ __forceinline__ unsigned short f2bf(float f) {
  unsigned u = __builtin_bit_cast(unsigned, f);
  u += 0x7FFFu + ((u >> 16) & 1u);
  return (unsigned short)(u >> 16);
}
__device__ __forceinline__ float bf2f(unsigned short s) {
  return __builtin_bit_cast(float, (unsigned)s << 16);
}

// LDS-only barrier (r15): avoids __syncthreads' implicit vmcnt(0) drain of
// prefetched loads / fire-and-forget stores. All barriers guard LDS only.
__device__ __forceinline__ void lds_barrier() {
  __builtin_amdgcn_sched_barrier(0);
  asm volatile("s_waitcnt lgkmcnt(0)" ::: "memory");
  __builtin_amdgcn_s_barrier();
  __builtin_amdgcn_sched_barrier(0);
}

// Swizzled byte offsets (T2, r11-proven): rows of 128 B / 256 B.
__device__ __forceinline__ int swz128(int row, int b) { return row * 128 + (b ^ ((row & 7) << 4)); }
__device__ __forceinline__ int swz256(int row, int b) { return row * 256 + (b ^ ((row & 15) << 4)); }

// Load the 3 input rows (main 8 px + packed left/right halo) for one (ch, pr)
// dw task straight into registers (no LDS round-trip; zero cross-thread reuse).
__device__ __forceinline__ void dw_load3(const __hip_bfloat16* __restrict__ base,
                                         int ch, int ih0, int iw0, int pr,
                                         uint4* __restrict__ m,
                                         unsigned* __restrict__ lr) {
#pragma unroll
  for (int kr = 0; kr < 3; ++kr) {
    int ii = ih0 + pr - 1 + kr;
    uint4 mv = {0u, 0u, 0u, 0u};
    unsigned lo = 0, hi = 0;
    if ((unsigned)ii < 256u) {
      const __hip_bfloat16* row = base + (((size_t)ch) << 16) + (ii << 8);
      mv = *(const uint4*)(row + iw0);                 // iw0 mult of 8 -> 16B aligned
      if (iw0 > 0)   lo = (unsigned)__builtin_bit_cast(unsigned short, row[iw0 - 1]);
      if (iw0 < 248) hi = (unsigned)__builtin_bit_cast(unsigned short, row[iw0 + 8]);
    }
    m[kr] = mv;
    lr[kr] = lo | (hi << 16);   // low = left halo, high = right halo
  }
}

// dw 3x3 for one (ch, pr) output row of 8 px, inputs in registers.
__device__ __forceinline__ void dw_regs(const uint4* __restrict__ m,
                                        const unsigned* __restrict__ lr,
                                        const float* __restrict__ wd,
                                        float* __restrict__ outv) {
#pragma unroll
  for (int pc = 0; pc < 8; ++pc) outv[pc] = 0.f;
#pragma unroll
  for (int kr = 0; kr < 3; ++kr) {
    uint4 rw = m[kr];
    float rv[10];
    rv[0] = bf2f((unsigned short)(rw.x & 0xFFFFu));
    rv[1] = bf2f((unsigned short)(rw.x >> 16));
    rv[2] = bf2f((unsigned short)(rw.y & 0xFFFFu));
    rv[3] = bf2f((unsigned short)(rw.y >> 16));
    rv[4] = bf2f((unsigned short)(rw.z & 0xFFFFu));
    rv[5] = bf2f((unsigned short)(rw.z >> 16));
    rv[6] = bf2f((unsigned short)(rw.w & 0xFFFFu));
    rv[7] = bf2f((unsigned short)(rw.w >> 16));
    rv[8] = bf2f((unsigned short)(lr[kr] >> 16));      // right
    rv[9] = bf2f((unsigned short)(lr[kr] & 0xFFFFu));  // left
#pragma unroll
    for (int s = 0; s < 3; ++s) {
      float wv = wd[kr * 3 + s];
#pragma unroll
      for (int pc = 0; pc < 8; ++pc) {
        int mm = pc + s - 1;
        float xv = (mm < 0) ? rv[9] : rv[mm];
        outv[pc] = fmaf(wv, xv, outv[pc]);
      }
    }
  }
}

// =======================================================================
// Kernel 1: rolled 1x1 conv as bf16 MFMA GEMM.
// ROUND-17: epilogue restructured. Old: 192 scalar 2B global stores/thread
// (2B bursts per lane, ~800 addr-calc VALU ops). New: each wave stages its
// 32-och x 64-px half-tile in a WAVE-PRIVATE LDS buffer (no barrier: same-
// wave ds ordering), then stores uint4 (8 bf16) with 128B-contiguous runs
// per och row -> 24 global store insts/thread. LDS 52.2 KB -> 3 blocks/CU.
// =======================================================================
__global__ __launch_bounds__(256) void k_qkv_mfma(const float* __restrict__ x,
                                                  const float* __restrict__ wq,
                                                  __hip_bfloat16* __restrict__ qkv) {
  __shared__ unsigned short x_s[128 * 136];   // [px][c]  (34816 B)
  __shared__ unsigned short stw[4][32][72];   // wave-private out tiles (18432 B)

  int blk = blockIdx.x;                 // 4 b x 256 i x 2 j-half
  int b = blk >> 9, i = (blk >> 1) & 255, jh = blk & 1;
  int j0 = jh << 7;
  int si = (i + 4) & 255;               // roll(-4): source row
  int t = threadIdx.x;

  {
    int c0 = (t & 63) << 1;
    int jb = (t >> 6) << 5;
    const float* xr0 = x + (((size_t)(b * CC + c0)) << 16) + (si << 8);
    const float* xr1 = xr0 + HW;
#pragma unroll
    for (int u = 0; u < 8; ++u) {
      int jj = jb + (u << 2);
      int sj = j0 + jj + 4;
      float v0[4], v1[4];
      if (sj + 3 <= 255) {
        *(float4*)v0 = *(const float4*)(xr0 + sj);
        *(float4*)v1 = *(const float4*)(xr1 + sj);
      } else {
#pragma unroll
        for (int e = 0; e < 4; ++e) {
          int s = (sj + e) & 255;
          v0[e] = xr0[s];
          v1[e] = xr1[s];
        }
      }
#pragma unroll
      for (int e = 0; e < 4; ++e) {
        unsigned pk = (unsigned)f2bf(v0[e]) | ((unsigned)f2bf(v1[e]) << 16);
        *(unsigned*)&x_s[(jj + e) * 136 + c0] = pk;
      }
    }
  }
  __syncthreads();

  int w = t >> 6;
  int lane = t & 63;
  int col = lane & 15;
  int kg = lane >> 4;

#pragma unroll 1
  for (int oi = 0; oi < 3; ++oi) {
    int m0 = oi * 128 + w * 32;
    bf16x8 afr[2][4];
#pragma unroll
    for (int mt = 0; mt < 2; ++mt) {
      const float* wr = wq + (m0 + mt * 16 + col) * CC + kg * 8;
#pragma unroll
      for (int ks = 0; ks < 4; ++ks) {
        float wa[4], wb[4];
        *(float4*)wa = *(const float4*)(wr + ks * 32);
        *(float4*)wb = *(const float4*)(wr + ks * 32 + 4);
        bf16x8 f;
#pragma unroll
        for (int e = 0; e < 4; ++e) {
          f[e] = (short)f2bf(wa[e]);
          f[e + 4] = (short)f2bf(wb[e]);
        }
        afr[mt][ks] = f;
      }
    }
#pragma unroll 1
    for (int hh = 0; hh < 2; ++hh) {        // px half: 0..63 / 64..127
#pragma unroll 1
      for (int nn = 0; nn < 4; ++nn) {
        int px = (hh * 4 + nn) * 16 + col;
        f32x4 acc0 = {0.f, 0.f, 0.f, 0.f};
        f32x4 acc1 = {0.f, 0.f, 0.f, 0.f};
#pragma unroll
        for (int ks = 0; ks < 4; ++ks) {
          bf16x8 bfr = *(const bf16x8*)&x_s[px * 136 + ks * 32 + kg * 8];
          acc0 = __builtin_amdgcn_mfma_f32_16x16x32_bf16(afr[0][ks], bfr, acc0, 0, 0, 0);
          acc1 = __builtin_amdgcn_mfma_f32_16x16x32_bf16(afr[1][ks], bfr, acc1, 0, 0, 0);
        }
        // stage to wave-private LDS tile [och_local][px_local]
#pragma unroll
        for (int r = 0; r < 4; ++r) {
          stw[w][kg * 4 + r][nn * 16 + col] = f2bf(acc0[r]);
          stw[w][16 + kg * 4 + r][nn * 16 + col] = f2bf(acc1[r]);
        }
      }
      // same-wave ds_write -> ds_read ordering (no cross-wave dependency)
      asm volatile("s_waitcnt lgkmcnt(0)" ::: "memory");
      __builtin_amdgcn_sched_barrier(0);
      // coalesced uint4 stores: lanes 0..7 cover one och row's 64 px = 128 B
#pragma unroll
      for (int u = 0; u < 4; ++u) {
        int task = u * 64 + lane;
        int ol = task >> 3, pg = task & 7;
        uint4 vv = *(const uint4*)&stw[w][ol][pg * 8];
        int och = m0 + ol;
        int g = och >> 7, c = och & 127;
        int j = j0 + hh * 64 + pg * 8;
        *(uint4*)(qkv + (((size_t)((g * NB + b) * CC + c)) << 16) + (i << 8) + j) = vv;
      }
    }
  }
}

// =======================================================================
// Kernel 2 (FUSED, r15 verbatim — equal-best; 5 concurrency attempts all
// null, so the structure is frozen while k_qkv is optimized):
//   RB [0,16K):    q_t [128c x 128B swz128] -> v_t [64p x 256B swz256] -> po_t
//   RC [16K,32K):  k_t [swz128] -> a_t half [128d x 64c swz128], TWO passes
//   sq [32K,33K):  [2 g][2 contrib][64 px]
// =======================================================================
__global__ __launch_bounds__(256) void k_fused(const __hip_bfloat16* __restrict__ qkv,
                                               const float* __restrict__ wdw,
                                               const float* __restrict__ temp_p,
                                               const float* __restrict__ wp,
                                               float* __restrict__ attn_out,
                                               float* __restrict__ y) {
  __shared__ __align__(16) char smem[33792];
  char* RB = smem;
  char* RC = smem + 16384;
  float* sq = (float*)(smem + 32768);   // 256 floats

  int bid = blockIdx.x;
  int blk = ((bid & 7) << 9) + (bid >> 3);   // XCD swizzle (4096 % 8 == 0)
  int b = blk >> 10, n = blk & 1023;
  int ih0 = (n >> 5) << 3, iw0 = (n & 31) << 3;
  int t = threadIdx.x;
  int ch_l = t & 15, grp = t >> 4;
  int pr = grp & 7, contrib = grp >> 3;      // 4 dw tasks share pr
  int wv = t >> 6, lane = t & 63;
  int col = lane & 15, kg = lane >> 4;
  float tau = temp_p[0];
  const __hip_bfloat16* qb = qkv + (((size_t)(b * CC)) << 16);
  const __hip_bfloat16* kb = qb + (((size_t)(NB * CC)) << 16);
  const __hip_bfloat16* vb = qb + (((size_t)(2 * NB * CC)) << 16);

  uint4 m[12];
  unsigned lr[12];
  float outv[4][8];
  float ssq[8];

  // ---- P0: q loads -> regs; dw q; ssq -> LDS
#pragma unroll
  for (int itk = 0; itk < 4; ++itk) {
    int ch = ((contrib + 2 * itk) << 4) + ch_l;
    dw_load3(qb, ch, ih0, iw0, pr, &m[itk * 3], &lr[itk * 3]);
  }
#pragma unroll
  for (int pc = 0; pc < 8; ++pc) ssq[pc] = 0.f;
#pragma unroll
  for (int itk = 0; itk < 4; ++itk) {
    int ch = ((contrib + 2 * itk) << 4) + ch_l;
    float wd[9];
#pragma unroll
    for (int kk = 0; kk < 9; ++kk) wd[kk] = wdw[ch * 9 + kk];
    dw_regs(&m[itk * 3], &lr[itk * 3], wd, outv[itk]);
#pragma unroll
    for (int pc = 0; pc < 8; ++pc) ssq[pc] = fmaf(outv[itk][pc], outv[itk][pc], ssq[pc]);
  }
#pragma unroll
  for (int pc = 0; pc < 8; ++pc) {
    float s = ssq[pc];
    s += __shfl_xor(s, 1); s += __shfl_xor(s, 2);
    s += __shfl_xor(s, 4); s += __shfl_xor(s, 8);
    ssq[pc] = s;
  }
  if (ch_l == 0) {
#pragma unroll
    for (int pc = 0; pc < 8; ++pc) sq[contrib * 64 + pr * 8 + pc] = ssq[pc];
  }
  lds_barrier();                                     // B1 (q ssq ready)

  // ---- P1: issue k loads; q scale + q_t write; dw k; k ssq -> LDS
  {
    uint4 m2[12];
    unsigned lr2[12];
#pragma unroll
    for (int itk = 0; itk < 4; ++itk) {
      int ch = ((contrib + 2 * itk) << 4) + ch_l;
      dw_load3(kb, ch, ih0, iw0, pr, &m2[itk * 3], &lr2[itk * 3]);
    }
    {
      float psv[8];
#pragma unroll
      for (int pc = 0; pc < 8; ++pc) {
        float s = sq[pr * 8 + pc] + sq[64 + pr * 8 + pc];
        psv[pc] = 1.f / fmaxf(sqrtf(s), 1e-12f);
      }
#pragma unroll
      for (int itk = 0; itk < 4; ++itk) {
        int ch = ((contrib + 2 * itk) << 4) + ch_l;
        unsigned short o8[8];
#pragma unroll
        for (int pc = 0; pc < 8; ++pc) o8[pc] = f2bf(outv[itk][pc] * psv[pc]);
        *(uint4*)(RB + swz128(ch, pr * 16)) = *(const uint4*)o8;
      }
    }
#pragma unroll
    for (int pc = 0; pc < 8; ++pc) ssq[pc] = 0.f;
#pragma unroll
    for (int itk = 0; itk < 4; ++itk) {
      int ch = ((contrib + 2 * itk) << 4) + ch_l;
      float wd[9];
#pragma unroll
      for (int kk = 0; kk < 9; ++kk) wd[kk] = wdw[(CC + ch) * 9 + kk];
      dw_regs(&m2[itk * 3], &lr2[itk * 3], wd, outv[itk]);
#pragma unroll
      for (int pc = 0; pc < 8; ++pc) ssq[pc] = fmaf(outv[itk][pc], outv[itk][pc], ssq[pc]);
    }
  }
#pragma unroll
  for (int pc = 0; pc < 8; ++pc) {
    float s = ssq[pc];
    s += __shfl_xor(s, 1); s += __shfl_xor(s, 2);
    s += __shfl_xor(s, 4); s += __shfl_xor(s, 8);
    ssq[pc] = s;
  }
  if (ch_l == 0) {
#pragma unroll
    for (int pc = 0; pc < 8; ++pc) sq[128 + contrib * 64 + pr * 8 + pc] = ssq[pc];
  }
  lds_barrier();                                     // B2 (k ssq ready)

  // ---- P2: k scale (tau folded) + k_t write
  {
    float psv[8];
#pragma unroll
    for (int pc = 0; pc < 8; ++pc) {
      float s = sq[128 + pr * 8 + pc] + sq[192 + pr * 8 + pc];
      psv[pc] = tau / fmaxf(sqrtf(s), 1e-12f);
    }
#pragma unroll
    for (int itk = 0; itk < 4; ++itk) {
      int ch = ((contrib + 2 * itk) << 4) + ch_l;
      unsigned short o8[8];
#pragma unroll
      for (int pc = 0; pc < 8; ++pc) o8[pc] = f2bf(outv[itk][pc] * psv[pc]);
      *(uint4*)(RC + swz128(ch, pr * 16)) = *(const uint4*)o8;
    }
  }
  lds_barrier();                                     // B3 (q_t + k_t ready)

  // ---- P3: QK^T; relu; attn fp32 write; keep pa; issue v loads
  int c0 = wv * 32;
  f32x4 pa0[8], pa1[8];
  {
    bf16x8 afr[2][2];
#pragma unroll
    for (int mt = 0; mt < 2; ++mt)
#pragma unroll
      for (int ks = 0; ks < 2; ++ks)
        afr[mt][ks] = *(const bf16x8*)(RB + swz128(c0 + mt * 16 + col, ks * 64 + kg * 16));
    float* ao = attn_out + ((size_t)blk << 14);   // 128*128 per window
#pragma unroll
    for (int dt = 0; dt < 8; ++dt) {
      bf16x8 b0 = *(const bf16x8*)(RC + swz128(dt * 16 + col, kg * 16));
      bf16x8 b1 = *(const bf16x8*)(RC + swz128(dt * 16 + col, 64 + kg * 16));
      f32x4 a0 = {0.f, 0.f, 0.f, 0.f};
      f32x4 a1 = {0.f, 0.f, 0.f, 0.f};
      a0 = __builtin_amdgcn_mfma_f32_16x16x32_bf16(afr[0][0], b0, a0, 0, 0, 0);
      a0 = __builtin_amdgcn_mfma_f32_16x16x32_bf16(afr[0][1], b1, a0, 0, 0, 0);
      a1 = __builtin_amdgcn_mfma_f32_16x16x32_bf16(afr[1][0], b0, a1, 0, 0, 0);
      a1 = __builtin_amdgcn_mfma_f32_16x16x32_bf16(afr[1][1], b1, a1, 0, 0, 0);
#pragma unroll
      for (int r = 0; r < 4; ++r) {
        a0[r] = fmaxf(a0[r], 0.f);
        a1[r] = fmaxf(a1[r], 0.f);
        ao[((c0 + kg * 4 + r) << 7) + dt * 16 + col] = a0[r];
        ao[((c0 + 16 + kg * 4 + r) << 7) + dt * 16 + col] = a1[r];
      }
      pa0[dt] = a0;
      pa1[dt] = a1;
    }
  }
#pragma unroll
  for (int itk = 0; itk < 4; ++itk) {
    int ch = ((contrib + 2 * itk) << 4) + ch_l;
    dw_load3(vb, ch, ih0, iw0, pr, &m[itk * 3], &lr[itk * 3]);
  }
  lds_barrier();                                     // B4 (q_t/k_t reads done)

  // ---- P4: dw v -> v_t [p][c] swz256 (over dead q_t); waves 0,1 a_t half0
#pragma unroll
  for (int itk = 0; itk < 4; ++itk) {
    int ch = ((contrib + 2 * itk) << 4) + ch_l;
    float wd[9];
#pragma unroll
    for (int kk = 0; kk < 9; ++kk) wd[kk] = wdw[(2 * CC + ch) * 9 + kk];
    float vo[8];
    dw_regs(&m[itk * 3], &lr[itk * 3], wd, vo);
#pragma unroll
    for (int pc = 0; pc < 8; ++pc)
      *(unsigned short*)(RB + swz256(pr * 8 + pc, ch * 2)) = f2bf(vo[pc]);
  }
  if (wv < 2) {
#pragma unroll
    for (int dt = 0; dt < 8; ++dt)
#pragma unroll
      for (int r = 0; r < 4; ++r) {
        int d = dt * 16 + col;
        *(unsigned short*)(RC + swz128(d, (c0 + kg * 4 + r) * 2)) = f2bf(pa0[dt][r]);
        *(unsigned short*)(RC + swz128(d, (c0 + 16 + kg * 4 + r) * 2)) = f2bf(pa1[dt][r]);
      }
  }
  lds_barrier();                                     // B5 (v_t + a_t half0 ready)

  // ---- P5: PV part1 (ks 0,1 -> c 0..63)
  f32x4 pacc[8];
#pragma unroll
  for (int dt = 0; dt < 8; ++dt) pacc[dt] = {0.f, 0.f, 0.f, 0.f};
#pragma unroll
  for (int ks = 0; ks < 2; ++ks) {
    bf16x8 va = *(const bf16x8*)(RB + swz256(wv * 16 + col, ks * 64 + kg * 16));
#pragma unroll
    for (int dt = 0; dt < 8; ++dt) {
      bf16x8 bf = *(const bf16x8*)(RC + swz128(dt * 16 + col, (ks & 1) * 64 + kg * 16));
      pacc[dt] = __builtin_amdgcn_mfma_f32_16x16x32_bf16(va, bf, pacc[dt], 0, 0, 0);
    }
  }
  lds_barrier();                                     // B6 (half0 reads done)

  // ---- P6: waves 2,3 write a_t half1 (c 64..127)
  if (wv >= 2) {
    int cl0 = c0 - 64;   // 0 or 32
#pragma unroll
    for (int dt = 0; dt < 8; ++dt)
#pragma unroll
      for (int r = 0; r < 4; ++r) {
        int d = dt * 16 + col;
        *(unsigned short*)(RC + swz128(d, (cl0 + kg * 4 + r) * 2)) = f2bf(pa0[dt][r]);
        *(unsigned short*)(RC + swz128(d, (cl0 + 16 + kg * 4 + r) * 2)) = f2bf(pa1[dt][r]);
      }
  }
  lds_barrier();                                     // B7 (a_t half1 ready)

  // ---- P7: PV part2 (ks 2,3 -> c 64..127)
#pragma unroll
  for (int ks = 2; ks < 4; ++ks) {
    bf16x8 va = *(const bf16x8*)(RB + swz256(wv * 16 + col, ks * 64 + kg * 16));
#pragma unroll
    for (int dt = 0; dt < 8; ++dt) {
      bf16x8 bf = *(const bf16x8*)(RC + swz128(dt * 16 + col, (ks & 1) * 64 + kg * 16));
      pacc[dt] = __builtin_amdgcn_mfma_f32_16x16x32_bf16(va, bf, pacc[dt], 0, 0, 0);
    }
  }
  lds_barrier();                                     // B8 (v_t reads done)

  // ---- P8: po_t [p][d] swz256 (over dead v_t)
#pragma unroll
  for (int dt = 0; dt < 8; ++dt)
#pragma unroll
    for (int r = 0; r < 4; ++r)
      *(unsigned short*)(RB + swz256(wv * 16 + kg * 4 + r, (dt * 16 + col) * 2)) =
          f2bf(pacc[dt][r]);
  lds_barrier();                                     // B9 (po_t ready)

  // ---- P9: proj (Wp A-frags from global, L2-resident) + fused unwindow/roll
  {
    int p = wv * 16 + col;
    bf16x8 bfr[4];
#pragma unroll
    for (int ks = 0; ks < 4; ++ks)
      bfr[ks] = *(const bf16x8*)(RB + swz256(p, ks * 64 + kg * 16));
    int i_f = (((n >> 5) << 3) + (p >> 3) + 4) & 255;
    int j_f = (((n & 31) << 3) + (p & 7) + 4) & 255;
    float* yp = y + (((size_t)b * CC) << 16) + (i_f << 8) + j_f;
#pragma unroll
    for (int mt = 0; mt < 8; ++mt) {
      bf16x8 afr[4];
      const float* wr = wp + (mt * 16 + col) * CC + kg * 8;
#pragma unroll
      for (int ks = 0; ks < 4; ++ks) {
        float wa[4], wb[4];
        *(float4*)wa = *(const float4*)(wr + ks * 32);
        *(float4*)wb = *(const float4*)(wr + ks * 32 + 4);
        bf16x8 f;
#pragma unroll
        for (int e = 0; e < 4; ++e) {
          f[e] = (short)f2bf(wa[e]);
          f[e + 4] = (short)f2bf(wb[e]);
        }
        afr[ks] = f;
      }
      f32x4 acc = {0.f, 0.f, 0.f, 0.f};
#pragma unroll
      for (int ks = 0; ks < 4; ++ks)
        acc = __builtin_amdgcn_mfma_f32_16x16x32_bf16(afr[ks], bfr[ks], acc, 0, 0, 0);
#pragma unroll
      for (int r = 0; r < 4; ++r) {
        int och = mt * 16 + kg * 4 + r;
        yp[(size_t)och << 16] = acc[r];
      }
    }
  }
}

extern "C" void kernel_launch(void* const* d_in, const int* in_sizes, int n_in,
                              void* d_out, int out_size, void* d_ws, size_t ws_size,
                              hipStream_t stream) {
  const float* x = (const float*)d_in[0];
  const float* w_qkv = (const float*)d_in[1];
  const float* w_dw = (const float*)d_in[2];
  const float* w_proj = (const float*)d_in[3];
  const float* temp = (const float*)d_in[4];
  float* y = (float*)d_out;
  float* attn = (float*)d_out + (size_t)NB * CC * HW;   // y first, then attn

  // d_ws (bf16): qkv [3][b][c][hw] = 201 MB.
  __hip_bfloat16* qkv = (__hip_bfloat16*)d_ws;

  k_qkv_mfma<<<2048, 256, 0, stream>>>(x, w_qkv, qkv);
  k_fused<<<4096, 256, 0, stream>>>(qkv, w_dw, temp, w_proj, attn, y);
}